// Round 9
// baseline (190.184 us; speedup 1.0000x reference)
//
#include <hip/hip_runtime.h>
#include <stdint.h>

#define SS 2048

typedef __attribute__((ext_vector_type(8))) short short8;
typedef __attribute__((ext_vector_type(4))) float f32x4;
typedef __attribute__((ext_vector_type(16))) float f32x16;

static __device__ __forceinline__ unsigned short f2bf(float f) {
    uint32_t u = __builtin_bit_cast(uint32_t, f);
    u += 0x7fffu + ((u >> 16) & 1u);
    return (unsigned short)(u >> 16);
}

static __device__ __forceinline__ uint32_t cvtpk(float lo, float hi) {
    uint32_t r;
    asm("v_cvt_pk_bf16_f32 %0, %1, %2" : "=v"(r) : "v"(lo), "v"(hi));
    return r;
}

static __device__ __forceinline__ void async16(const unsigned short* g, unsigned short* l) {
    __builtin_amdgcn_global_load_lds(
        (const __attribute__((address_space(1))) uint32_t*)g,
        (__attribute__((address_space(3))) uint32_t*)l, 16, 0, 0);
}

// ---------------- fused cast fp32 -> bf16 (x | W_qkv | W_o) ----------------
__global__ void cast3(const float* __restrict__ a, const float* __restrict__ b,
                      const float* __restrict__ c,
                      unsigned short* __restrict__ da, unsigned short* __restrict__ db,
                      unsigned short* __restrict__ dc_) {
    int i = (blockIdx.x * 256 + threadIdx.x) * 4;
    const float* s;
    unsigned short* d;
    if (i < 8388608)        { s = a + i;              d = da + i; }
    else if (i < 11534336)  { s = b + (i - 8388608);  d = db + (i - 8388608); }
    else                    { s = c + (i - 11534336); d = dc_ + (i - 11534336); }
    float4 v = *(const float4*)s;
    ushort4 o;
    o.x = f2bf(v.x); o.y = f2bf(v.y); o.z = f2bf(v.z); o.w = f2bf(v.w);
    *(ushort4*)d = o;
}

// ================= 128x256 4-phase pipelined QKV GEMM =================
// C[8192,3072] = A[8192,1024]*B[3072,1024]^T -> Tqk / Vt routing.
// 512 thr = 8 waves (2M x 4N); per-wave output 64x64; BK=64.
// LDS 96KB: A 2buf x 2half(wm) x [64][64], B 2buf x 2half(wn>>1) x [128][64].
// Both-sides XOR swizzle (LDS col16 = global col16 ^ (row&7)) via pre-swizzled
// global source + swizzled ds_read. Per-wave per-tile loads, issue order
// [a0,b0 | b1,a1 | b2 | b3]; windows vmcnt(3)/4/4/- keep 5-6 loads in flight.
// Grid 768 = 3 EXACT occupancy rounds at 1 block/CU (fixes r5's 1.5/2 waste).
__global__ __launch_bounds__(512, 1) void gemm0_qkv(
        const unsigned short* __restrict__ A,
        const unsigned short* __restrict__ B,
        unsigned short* __restrict__ Tqk,
        unsigned short* __restrict__ Vt) {
    extern __shared__ char sm[];
    const int t = threadIdx.x, w = t >> 6, l = t & 63;
    const int wm = w >> 2, wn = w & 3;
    const int l15 = l & 15, l4 = l >> 4;
    const int lr = l >> 3, lc = l & 7;

    // XCD-bijective: 768 blocks, 96 per XCD; bm fastest for B-panel L2 reuse
    const int lin = blockIdx.x;
    const int wg = (lin & 7) * 96 + (lin >> 3);
    const int bm = wg & 63, bn = wg >> 6;
    const int m0 = bm * 128, n0 = bn * 256;

    const int u_a = wn;                       // 4 waves per A-half(wm)
    const int u_b = wm * 2 + (wn & 1);        // 4 waves per B-half(wn>>1)
    const int scol = (lc ^ lr) * 8;           // pre-swizzled source col (elements)

    const unsigned short* Ab = A + (size_t)(m0 + wm * 64 + u_a * 8 + lr) * 1024 + scol;
    const unsigned short* Bb = B + (size_t)(n0 + (wn >> 1) * 128 + u_b * 8 + lr) * 1024 + scol;

    char* const smA = sm + wm * 8192;                     // + buf*16384 + j*4096
    char* const smB = sm + 32768 + (wn >> 1) * 16384;     // + buf*32768 + brow_j*128
    const int adst = (u_a * 8 + lr) * 128 + lc * 16;
    const int bdst = (u_b * 8 + lr) * 128 + lc * 16;

#define SA(j, T, buf) async16(Ab + (size_t)(j) * 32768 + (size_t)(T) * 64, \
        (unsigned short*)(smA + (buf) * 16384 + (j) * 4096 + adst))
#define SB(j, T, buf) async16(Bb + (size_t)((((j) & 1) * 64 + ((j) >> 1) * 32)) * 1024 + (size_t)(T) * 64, \
        (unsigned short*)(smB + (buf) * 32768 + ((((j) & 1) * 64 + ((j) >> 1) * 32)) * 128 + bdst))

    const int rc0 = (l4 ^ (l15 & 7)) * 16;          // kk=0 swizzled col
    const int rc1 = ((4 + l4) ^ (l15 & 7)) * 16;    // kk=1
    const int brow = ((wn & 1) * 64 + l15) * 128;

    f32x4 acc[4][4] = {};
    short8 af[2][2], bfr[2][2];

#define RD_A(lo) { const char* Ar = smA + cur * 16384 + (lo) * 4096 + l15 * 128;     \
    af[0][0] = *(const short8*)(Ar + rc0);                                           \
    af[0][1] = *(const short8*)(Ar + rc1);                                           \
    af[1][0] = *(const short8*)(Ar + 2048 + rc0);                                    \
    af[1][1] = *(const short8*)(Ar + 2048 + rc1); }
#define RD_B(hi) { const char* Br = smB + cur * 32768 + brow + (hi) * 4096;          \
    bfr[0][0] = *(const short8*)(Br + rc0);                                          \
    bfr[0][1] = *(const short8*)(Br + rc1);                                          \
    bfr[1][0] = *(const short8*)(Br + 2048 + rc0);                                   \
    bfr[1][1] = *(const short8*)(Br + 2048 + rc1); }
#define MM(R, C) _Pragma("unroll") for (int m = 0; m < 2; ++m)                       \
    _Pragma("unroll") for (int n = 0; n < 2; ++n) {                                  \
        acc[(R)*2+m][(C)*2+n] = __builtin_amdgcn_mfma_f32_16x16x32_bf16(             \
            af[m][0], bfr[n][0], acc[(R)*2+m][(C)*2+n], 0, 0, 0);                    \
        acc[(R)*2+m][(C)*2+n] = __builtin_amdgcn_mfma_f32_16x16x32_bf16(             \
            af[m][1], bfr[n][1], acc[(R)*2+m][(C)*2+n], 0, 0, 0); }
#define BAR __builtin_amdgcn_s_barrier()
#define SP1 __builtin_amdgcn_s_setprio(1)
#define SP0 __builtin_amdgcn_s_setprio(0)

    // prologue: tile 0 -> buf 0, order [a0,b0,b1,a1,b2,b3]
    SA(0, 0, 0); SB(0, 0, 0); SB(1, 0, 0); SA(1, 0, 0); SB(2, 0, 0); SB(3, 0, 0);

    for (int tt = 0; tt < 16; ++tt) {
        const int cur = tt & 1, nxt = cur ^ 1;
        const int Tn = (tt + 1 < 16) ? tt + 1 : 0;   // dummy restage keeps counts exact
        // p0: needs a0 (A rows 0-31), b0/b1 (B hi=0 rows)
        asm volatile("s_waitcnt vmcnt(3)" ::: "memory"); BAR;
        RD_A(0); RD_B(0);
        SA(0, Tn, nxt); SB(0, Tn, nxt);
        SP1; MM(0, 0); SP0; BAR;
        // p1: needs a1 (A rows 32-63)
        asm volatile("s_waitcnt vmcnt(4)" ::: "memory"); BAR;
        RD_A(1);
        SB(1, Tn, nxt); SA(1, Tn, nxt);
        SP1; MM(1, 0); SP0; BAR;
        // p2: needs b2/b3 (B hi=1 rows)
        asm volatile("s_waitcnt vmcnt(4)" ::: "memory"); BAR;
        RD_B(1);
        SB(2, Tn, nxt);
        SP1; MM(1, 1); SP0; BAR;
        // p3: re-reads a0 (guaranteed), finishes staging
        RD_A(0);
        SB(3, Tn, nxt);
        SP1; MM(0, 1); SP0; BAR;
    }
#undef SA
#undef SB
#undef RD_A
#undef RD_B
#undef MM
#undef BAR
#undef SP1
#undef SP0

    // epilogue: QKV routing (verified mapping)
#pragma unroll
    for (int fm = 0; fm < 4; ++fm) {
        int rbase = m0 + wm * 64 + fm * 16 + l4 * 4;
#pragma unroll
        for (int fn = 0; fn < 4; ++fn) {
            int c = n0 + wn * 64 + fn * 16 + l15;
            f32x4 v = acc[fm][fn];
            if (c < 2048) {
                float sc = (c < 1024) ? 0.18033688f : 1.0f;  // Q: log2e/8
#pragma unroll
                for (int r = 0; r < 4; ++r)
                    Tqk[(size_t)(rbase + r) * 2048 + c] = f2bf(v[r] * sc);
            } else {
                int vv = c - 2048;
                int hh = vv >> 6, d = vv & 63;
                int bb = rbase >> 11, s = rbase & 2047;
                ushort4 pk;
                pk.x = f2bf(v[0]); pk.y = f2bf(v[1]); pk.z = f2bf(v[2]); pk.w = f2bf(v[3]);
                *(ushort4*)&Vt[((size_t)(bb * 16 + hh) * 64 + d) * 2048 + s] = pk;
            }
        }
    }
}

// ---------------- 128^2 GEMM (out-proj): C fp32 = A[M,K] * B[N,K]^T ----------------
__global__ void gemm_bt(const unsigned short* __restrict__ A,
                        const unsigned short* __restrict__ Bm,
                        float* __restrict__ C, int K) {
    __shared__ unsigned short As[128 * 64];
    __shared__ unsigned short Bs[128 * 64];
    const int t = threadIdx.x;
    const int w = t >> 6, l = t & 63;
    const int wm = w >> 1, wn = w & 1;
    const int l15 = l & 15, l4 = l >> 4;
    const int m0 = blockIdx.x * 128, n0 = blockIdx.y * 128;
    const int srow = t >> 3;
    const int scol = (t & 7) * 8;

    f32x4 acc[4][4] = {};

    for (int k0 = 0; k0 < K; k0 += 64) {
#pragma unroll
        for (int r = 0; r < 4; ++r) {
            int row = r * 32 + srow;
            async16(A + (size_t)(m0 + row) * K + k0 + scol, (unsigned short*)&As[row * 64 + scol]);
        }
#pragma unroll
        for (int r = 0; r < 4; ++r) {
            int row = r * 32 + srow;
            async16(Bm + (size_t)(n0 + row) * K + k0 + scol, (unsigned short*)&Bs[row * 64 + scol]);
        }
        __syncthreads();
#pragma unroll
        for (int kk = 0; kk < 64; kk += 32) {
            short8 af[4], bfr[4];
#pragma unroll
            for (int m = 0; m < 4; ++m)
                af[m] = *(const short8*)&As[(wm * 64 + m * 16 + l15) * 64 + kk + l4 * 8];
#pragma unroll
            for (int n = 0; n < 4; ++n)
                bfr[n] = *(const short8*)&Bs[(wn * 64 + n * 16 + l15) * 64 + kk + l4 * 8];
#pragma unroll
            for (int m = 0; m < 4; ++m)
#pragma unroll
                for (int n = 0; n < 4; ++n)
                    acc[m][n] = __builtin_amdgcn_mfma_f32_16x16x32_bf16(af[m], bfr[n], acc[m][n], 0, 0, 0);
        }
        __syncthreads();
    }

#pragma unroll
    for (int m = 0; m < 4; ++m) {
        int rbase = m0 + wm * 64 + m * 16 + l4 * 4;
#pragma unroll
        for (int n = 0; n < 4; ++n) {
            int c = n0 + wn * 64 + n * 16 + l15;
            f32x4 v = acc[m][n];
#pragma unroll
            for (int r = 0; r < 4; ++r)
                C[(size_t)(rbase + r) * 1024 + c] = v[r];
        }
    }
}

// ---------------- Flash attention (round-5/8 structure, best measured) ----------------
__global__ __launch_bounds__(256, 4) void attn_kernel(
        const unsigned short* __restrict__ Tqk,
        const unsigned short* __restrict__ Vt,
        unsigned short* __restrict__ Out) {
    __shared__ unsigned short Ks[2][64 * 64];
    __shared__ unsigned short Vs[2][64 * 64];
    const int t = threadIdx.x;
    const int w = t >> 6, l = t & 63;
    const int lq = l & 31, hfl = l >> 5;

    const int lin = blockIdx.x;
    const int j = lin >> 3;
    const int bh = (lin & 7) * 8 + (j & 7);
    const int qt = j >> 3;
    const int b = bh >> 4, hh = bh & 15;
    const int qrow = qt * 128 + w * 32 + lq;

    short8 qf[4];
    const size_t trow = ((size_t)b * SS + qrow) * 2048;
#pragma unroll
    for (int dc = 0; dc < 4; ++dc)
        qf[dc] = *(const short8*)&Tqk[trow + hh * 64 + dc * 16 + hfl * 8];

    char* KsB = (char*)Ks;
    char* VsB = (char*)Vs;

    const int srow = t >> 3;
    const int scb = (t & 7) << 4;
    const int ssw = scb ^ ((srow & 7) << 4);
    const int sel = scb >> 1;

    const unsigned short* kp0 = Tqk + (size_t)b * SS * 2048 + 1024 + hh * 64 + (size_t)srow * 2048 + sel;
    const unsigned short* kp1 = kp0 + 32 * 2048;
    const unsigned short* vp0 = Vt + (size_t)bh * 64 * 2048 + (size_t)srow * 2048 + sel;
    const unsigned short* vp1 = vp0 + 32 * 2048;

    int4 kr0, kr1, vr0, vr1;
#define ISSUE()                                                                      \
    kr0 = *(const int4*)kp0; kr1 = *(const int4*)kp1;                                \
    vr0 = *(const int4*)vp0; vr1 = *(const int4*)vp1;
#define WRITE(buf)                                                                   \
    {                                                                                \
        char* kb = KsB + (buf) * 8192;                                               \
        char* vb = VsB + (buf) * 8192;                                               \
        *(int4*)(kb + srow * 128 + ssw) = kr0;                                       \
        *(int4*)(kb + (srow + 32) * 128 + ssw) = kr1;                                \
        *(int4*)(vb + srow * 128 + ssw) = vr0;                                       \
        *(int4*)(vb + (srow + 32) * 128 + ssw) = vr1;                                \
    }

    f32x16 oacc[2] = {};
    float la0 = 0.f, la1 = 0.f, la2 = 0.f, la3 = 0.f;

    ISSUE();
    WRITE(0);
    __syncthreads();

    for (int it = 0; it < 32; ++it) {
        const int cur = it & 1;
        const char* kb = KsB + cur * 8192;
        const char* vb = VsB + cur * 8192;
        const bool more = (it < 31);
        if (more) {
            kp0 += 64 * 2048; kp1 += 64 * 2048;
            vp0 += 64;        vp1 += 64;
            ISSUE();
        }

        f32x16 sa[2] = {};
        __builtin_amdgcn_s_setprio(1);
#pragma unroll
        for (int kvt = 0; kvt < 2; ++kvt) {
            int row = kvt * 32 + lq;
#pragma unroll
            for (int dc = 0; dc < 4; ++dc) {
                short8 kf = *(const short8*)(kb + row * 128 + ((dc * 32 + hfl * 16) ^ ((row & 7) << 4)));
                sa[kvt] = __builtin_amdgcn_mfma_f32_32x32x16_bf16(kf, qf[dc], sa[kvt], 0, 0, 0);
            }
        }
        __builtin_amdgcn_s_setprio(0);

#pragma unroll
        for (int kvt = 0; kvt < 2; ++kvt)
#pragma unroll
            for (int r = 0; r < 16; r += 4) {
                float p0 = __builtin_amdgcn_exp2f(sa[kvt][r + 0]);
                float p1 = __builtin_amdgcn_exp2f(sa[kvt][r + 1]);
                float p2 = __builtin_amdgcn_exp2f(sa[kvt][r + 2]);
                float p3 = __builtin_amdgcn_exp2f(sa[kvt][r + 3]);
                sa[kvt][r + 0] = p0; la0 += p0;
                sa[kvt][r + 1] = p1; la1 += p1;
                sa[kvt][r + 2] = p2; la2 += p2;
                sa[kvt][r + 3] = p3; la3 += p3;
            }

        short8 pb[4];
#pragma unroll
        for (int c = 0; c < 4; ++c) {
            int f = c >> 1, r0 = (c & 1) * 8;
            uint32_t v0 = cvtpk(sa[f][r0 + 0], sa[f][r0 + 1]);
            uint32_t v1 = cvtpk(sa[f][r0 + 2], sa[f][r0 + 3]);
            uint32_t v2 = cvtpk(sa[f][r0 + 4], sa[f][r0 + 5]);
            uint32_t v3 = cvtpk(sa[f][r0 + 6], sa[f][r0 + 7]);
            asm("v_permlane32_swap_b32 %0, %1" : "+v"(v0), "+v"(v2));
            asm("v_permlane32_swap_b32 %0, %1" : "+v"(v1), "+v"(v3));
            union { uint32_t u[4]; short8 s; } pbu;
            pbu.u[0] = v0;
            pbu.u[1] = v1;
            pbu.u[2] = v2;
            pbu.u[3] = v3;
            pb[c] = pbu.s;
        }

        __builtin_amdgcn_s_setprio(1);
#pragma unroll
        for (int dt = 0; dt < 2; ++dt) {
            int row0 = dt * 32 + lq;
#pragma unroll
            for (int c = 0; c < 4; ++c) {
                short8 vf = *(const short8*)(vb + row0 * 128 + ((c * 32 + hfl * 16) ^ ((row0 & 7) << 4)));
                oacc[dt] = __builtin_amdgcn_mfma_f32_32x32x16_bf16(vf, pb[c], oacc[dt], 0, 0, 0);
            }
        }
        __builtin_amdgcn_s_setprio(0);

        if (more) { WRITE(cur ^ 1); }
        __syncthreads();
    }
#undef ISSUE
#undef WRITE

    float l_run = (la0 + la1) + (la2 + la3);
    l_run += __shfl_xor(l_run, 32);
    float inv = 1.0f / l_run;
    const size_t obase = ((size_t)b * SS + qrow) * 1024 + hh * 64;
#pragma unroll
    for (int dt = 0; dt < 2; ++dt)
#pragma unroll
        for (int g = 0; g < 4; ++g) {
            int d0 = dt * 32 + 8 * g + 4 * hfl;
            ushort4 pk;
            pk.x = f2bf(oacc[dt][4 * g + 0] * inv);
            pk.y = f2bf(oacc[dt][4 * g + 1] * inv);
            pk.z = f2bf(oacc[dt][4 * g + 2] * inv);
            pk.w = f2bf(oacc[dt][4 * g + 3] * inv);
            *(ushort4*)&Out[obase + d0] = pk;
        }
}

// ---------------- launch ----------------
extern "C" void kernel_launch(void* const* d_in, const int* in_sizes, int n_in,
                              void* d_out, int out_size, void* d_ws, size_t ws_size,
                              hipStream_t stream) {
    const float* x    = (const float*)d_in[0];
    const float* wqkv = (const float*)d_in[1];
    const float* wo   = (const float*)d_in[2];

    unsigned short* ws  = (unsigned short*)d_ws;
    unsigned short* xb  = ws;                    // 8192x1024 bf16
    unsigned short* w1  = ws + 8388608;          // 3072x1024
    unsigned short* w2  = ws + 11534336;         // 1024x1024
    unsigned short* vt  = ws + 12582912;         // 64 heads x 64 d x 2048 s
    unsigned short* ao  = ws + 20971520;         // 8192x1024 attn out
    unsigned short* tqk = (unsigned short*)d_out; // Q|K scratch (bf16), overwritten by final GEMM

    (void)hipFuncSetAttribute((const void*)gemm0_qkv,
                              hipFuncAttributeMaxDynamicSharedMemorySize, 98304);

    cast3<<<12288, 256, 0, stream>>>(x, wqkv, wo, xb, w1, w2);
    gemm0_qkv<<<768, 512, 98304, stream>>>(xb, w1, tqk, vt);
    attn_kernel<<<1024, 256, 0, stream>>>(tqk, vt, ao);
    gemm_bt<<<dim3(64, 8), 256, 0, stream>>>(ao, w2, (float*)d_out, 1024);
}

// Round 10
// 187.642 us; speedup vs baseline: 1.0135x; 1.0135x over previous
//
#include <hip/hip_runtime.h>
#include <stdint.h>

#define SS 2048

typedef __attribute__((ext_vector_type(8))) short short8;
typedef __attribute__((ext_vector_type(4))) float f32x4;
typedef __attribute__((ext_vector_type(16))) float f32x16;

static __device__ __forceinline__ unsigned short f2bf(float f) {
    uint32_t u = __builtin_bit_cast(uint32_t, f);
    u += 0x7fffu + ((u >> 16) & 1u);
    return (unsigned short)(u >> 16);
}

static __device__ __forceinline__ uint32_t cvtpk(float lo, float hi) {
    uint32_t r;
    asm("v_cvt_pk_bf16_f32 %0, %1, %2" : "=v"(r) : "v"(lo), "v"(hi));
    return r;
}

static __device__ __forceinline__ void async16(const unsigned short* g, unsigned short* l) {
    __builtin_amdgcn_global_load_lds(
        (const __attribute__((address_space(1))) uint32_t*)g,
        (__attribute__((address_space(3))) uint32_t*)l, 16, 0, 0);
}

// ---------------- fused cast fp32 -> bf16 (x | W_qkv | W_o) ----------------
__global__ void cast3(const float* __restrict__ a, const float* __restrict__ b,
                      const float* __restrict__ c,
                      unsigned short* __restrict__ da, unsigned short* __restrict__ db,
                      unsigned short* __restrict__ dc_) {
    int i = (blockIdx.x * 256 + threadIdx.x) * 4;
    const float* s;
    unsigned short* d;
    if (i < 8388608)        { s = a + i;              d = da + i; }
    else if (i < 11534336)  { s = b + (i - 8388608);  d = db + (i - 8388608); }
    else                    { s = c + (i - 11534336); d = dc_ + (i - 11534336); }
    float4 v = *(const float4*)s;
    ushort4 o;
    o.x = f2bf(v.x); o.y = f2bf(v.y); o.z = f2bf(v.z); o.w = f2bf(v.w);
    *(ushort4*)d = o;
}

// ---------------- GEMM: C[M,N] = A[M,K] * B[N,K]^T (bf16 in, fp32 acc) ----------------
// MODE 0: QKV projection epilogue. cols<1024 -> Q*(log2e/8) -> Tqk bf16 (stride 2048)
//         1024<=c<2048 -> K -> Tqk; c>=2048 -> V written TRANSPOSED into Vt[(b,h),d][s]
// MODE 1: plain fp32 C (stride 1024)
template<int MODE>
__global__ void gemm_bt(const unsigned short* __restrict__ A,
                        const unsigned short* __restrict__ Bm,
                        void* __restrict__ Cout,
                        unsigned short* __restrict__ Vt,
                        int K) {
    __shared__ unsigned short As[128 * 64];
    __shared__ unsigned short Bs[128 * 64];
    const int t = threadIdx.x;
    const int w = t >> 6, l = t & 63;
    const int wm = w >> 1, wn = w & 1;
    const int l15 = l & 15, l4 = l >> 4;
    const int m0 = blockIdx.x * 128, n0 = blockIdx.y * 128;
    const int srow = t >> 3;
    const int scol = (t & 7) * 8;

    f32x4 acc[4][4] = {};

    for (int k0 = 0; k0 < K; k0 += 64) {
#pragma unroll
        for (int r = 0; r < 4; ++r) {
            int row = r * 32 + srow;
            async16(A + (size_t)(m0 + row) * K + k0 + scol, (unsigned short*)&As[row * 64 + scol]);
        }
#pragma unroll
        for (int r = 0; r < 4; ++r) {
            int row = r * 32 + srow;
            async16(Bm + (size_t)(n0 + row) * K + k0 + scol, (unsigned short*)&Bs[row * 64 + scol]);
        }
        __syncthreads();
#pragma unroll
        for (int kk = 0; kk < 64; kk += 32) {
            short8 af[4], bfr[4];
#pragma unroll
            for (int m = 0; m < 4; ++m)
                af[m] = *(const short8*)&As[(wm * 64 + m * 16 + l15) * 64 + kk + l4 * 8];
#pragma unroll
            for (int n = 0; n < 4; ++n)
                bfr[n] = *(const short8*)&Bs[(wn * 64 + n * 16 + l15) * 64 + kk + l4 * 8];
#pragma unroll
            for (int m = 0; m < 4; ++m)
#pragma unroll
                for (int n = 0; n < 4; ++n)
                    acc[m][n] = __builtin_amdgcn_mfma_f32_16x16x32_bf16(af[m], bfr[n], acc[m][n], 0, 0, 0);
        }
        __syncthreads();
    }

#pragma unroll
    for (int m = 0; m < 4; ++m) {
        int rbase = m0 + wm * 64 + m * 16 + l4 * 4;
#pragma unroll
        for (int n = 0; n < 4; ++n) {
            int c = n0 + wn * 64 + n * 16 + l15;
            f32x4 v = acc[m][n];
            if (MODE == 0) {
                if (c < 2048) {
                    float sc = (c < 1024) ? 0.18033688f : 1.0f;  // Q: log2e/8
                    unsigned short* T = (unsigned short*)Cout;
#pragma unroll
                    for (int r = 0; r < 4; ++r)
                        T[(size_t)(rbase + r) * 2048 + c] = f2bf(v[0 + r] * sc);
                } else {
                    int vv = c - 2048;
                    int hh = vv >> 6, d = vv & 63;
                    int bb = rbase >> 11, s = rbase & 2047;
                    ushort4 pk;
                    pk.x = f2bf(v[0]); pk.y = f2bf(v[1]); pk.z = f2bf(v[2]); pk.w = f2bf(v[3]);
                    *(ushort4*)&Vt[((size_t)(bb * 16 + hh) * 64 + d) * 2048 + s] = pk;
                }
            } else {
                float* C = (float*)Cout;
#pragma unroll
                for (int r = 0; r < 4; ++r)
                    C[(size_t)(rbase + r) * 1024 + c] = v[r];
            }
        }
    }
}

// ---------------- Flash attention (best measured structure) ----------------
// grid 1024 XCD-remapped, 256 thr = 4 waves, 32 q/wave, KVBLK=64, dbuf LDS,
// reg-staged async split (issue-early/write-late), unstabilized log2-domain
// softmax (Q pre-scaled by log2e/8), cvt_pk+permlane pack, per-lane l chains.
__global__ __launch_bounds__(256, 4) void attn_kernel(
        const unsigned short* __restrict__ Tqk,
        const unsigned short* __restrict__ Vt,
        unsigned short* __restrict__ Out) {
    __shared__ unsigned short Ks[2][64 * 64];
    __shared__ unsigned short Vs[2][64 * 64];
    const int t = threadIdx.x;
    const int w = t >> 6, l = t & 63;
    const int lq = l & 31, hfl = l >> 5;

    // XCD-bijective remap: each XCD's L2 holds only 8 heads' K/V (4MB)
    const int lin = blockIdx.x;
    const int j = lin >> 3;
    const int bh = (lin & 7) * 8 + (j & 7);
    const int qt = j >> 3;
    const int b = bh >> 4, hh = bh & 15;
    const int qrow = qt * 128 + w * 32 + lq;

    // Q fragments (pre-scaled by log2e/8 in GEMM epilogue)
    short8 qf[4];
    const size_t trow = ((size_t)b * SS + qrow) * 2048;
#pragma unroll
    for (int dc = 0; dc < 4; ++dc)
        qf[dc] = *(const short8*)&Tqk[trow + hh * 64 + dc * 16 + hfl * 8];

    char* KsB = (char*)Ks;
    char* VsB = (char*)Vs;

    // staging geometry: 256 threads x 2 rows x 16B cover 64x128B (swizzled)
    const int srow = t >> 3;              // 0..31 (second row = +32, same row&7)
    const int scb = (t & 7) << 4;         // byte col
    const int ssw = scb ^ ((srow & 7) << 4);
    const int sel = scb >> 1;             // element col

    const unsigned short* kp0 = Tqk + (size_t)b * SS * 2048 + 1024 + hh * 64 + (size_t)srow * 2048 + sel;
    const unsigned short* kp1 = kp0 + 32 * 2048;
    const unsigned short* vp0 = Vt + (size_t)bh * 64 * 2048 + (size_t)srow * 2048 + sel;
    const unsigned short* vp1 = vp0 + 32 * 2048;

    int4 kr0, kr1, vr0, vr1;
#define ISSUE()                                                                      \
    kr0 = *(const int4*)kp0; kr1 = *(const int4*)kp1;                                \
    vr0 = *(const int4*)vp0; vr1 = *(const int4*)vp1;
#define WRITE(buf)                                                                   \
    {                                                                                \
        char* kb = KsB + (buf) * 8192;                                               \
        char* vb = VsB + (buf) * 8192;                                               \
        *(int4*)(kb + srow * 128 + ssw) = kr0;                                       \
        *(int4*)(kb + (srow + 32) * 128 + ssw) = kr1;                                \
        *(int4*)(vb + srow * 128 + ssw) = vr0;                                       \
        *(int4*)(vb + (srow + 32) * 128 + ssw) = vr1;                                \
    }

    f32x16 oacc[2] = {};
    float la0 = 0.f, la1 = 0.f, la2 = 0.f, la3 = 0.f;

    ISSUE();
    WRITE(0);
    __syncthreads();

    for (int it = 0; it < 32; ++it) {
        const int cur = it & 1;
        const char* kb = KsB + cur * 8192;
        const char* vb = VsB + cur * 8192;
        const bool more = (it < 31);
        if (more) {
            kp0 += 64 * 2048; kp1 += 64 * 2048;
            vp0 += 64;        vp1 += 64;
            ISSUE();
        }

        // ---- S^T = K * Q ----
        f32x16 sa[2] = {};
        __builtin_amdgcn_s_setprio(1);
#pragma unroll
        for (int kvt = 0; kvt < 2; ++kvt) {
            int row = kvt * 32 + lq;
#pragma unroll
            for (int dc = 0; dc < 4; ++dc) {
                short8 kf = *(const short8*)(kb + row * 128 + ((dc * 32 + hfl * 16) ^ ((row & 7) << 4)));
                sa[kvt] = __builtin_amdgcn_mfma_f32_32x32x16_bf16(kf, qf[dc], sa[kvt], 0, 0, 0);
            }
        }
        __builtin_amdgcn_s_setprio(0);

        // ---- p = exp2(s); accumulate per-lane l (4 chains) ----
#pragma unroll
        for (int kvt = 0; kvt < 2; ++kvt)
#pragma unroll
            for (int r = 0; r < 16; r += 4) {
                float p0 = __builtin_amdgcn_exp2f(sa[kvt][r + 0]);
                float p1 = __builtin_amdgcn_exp2f(sa[kvt][r + 1]);
                float p2 = __builtin_amdgcn_exp2f(sa[kvt][r + 2]);
                float p3 = __builtin_amdgcn_exp2f(sa[kvt][r + 3]);
                sa[kvt][r + 0] = p0; la0 += p0;
                sa[kvt][r + 1] = p1; la1 += p1;
                sa[kvt][r + 2] = p2; la2 += p2;
                sa[kvt][r + 3] = p3; la3 += p3;
            }

        // ---- pack P -> B-operand frags via cvt_pk + permlane32_swap ----
        short8 pb[4];
#pragma unroll
        for (int c = 0; c < 4; ++c) {
            int f = c >> 1, r0 = (c & 1) * 8;
            uint32_t v0 = cvtpk(sa[f][r0 + 0], sa[f][r0 + 1]);
            uint32_t v1 = cvtpk(sa[f][r0 + 2], sa[f][r0 + 3]);
            uint32_t v2 = cvtpk(sa[f][r0 + 4], sa[f][r0 + 5]);
            uint32_t v3 = cvtpk(sa[f][r0 + 6], sa[f][r0 + 7]);
            asm("v_permlane32_swap_b32 %0, %1" : "+v"(v0), "+v"(v2));
            asm("v_permlane32_swap_b32 %0, %1" : "+v"(v1), "+v"(v3));
            union { uint32_t u[4]; short8 s; } pbu;
            pbu.u[0] = v0;
            pbu.u[1] = v1;
            pbu.u[2] = v2;
            pbu.u[3] = v3;
            pb[c] = pbu.s;
        }

        // ---- O^T += V^T * P^T ----
        __builtin_amdgcn_s_setprio(1);
#pragma unroll
        for (int dt = 0; dt < 2; ++dt) {
            int row0 = dt * 32 + lq;
#pragma unroll
            for (int c = 0; c < 4; ++c) {
                short8 vf = *(const short8*)(vb + row0 * 128 + ((c * 32 + hfl * 16) ^ ((row0 & 7) << 4)));
                oacc[dt] = __builtin_amdgcn_mfma_f32_32x32x16_bf16(vf, pb[c], oacc[dt], 0, 0, 0);
            }
        }
        __builtin_amdgcn_s_setprio(0);

        if (more) { WRITE(cur ^ 1); }
        __syncthreads();
    }
#undef ISSUE
#undef WRITE

    float l_run = (la0 + la1) + (la2 + la3);
    l_run += __shfl_xor(l_run, 32);
    float inv = 1.0f / l_run;
    // O epilogue: d = dt*32 + (r&3) + 8*(r>>2) + 4*hfl -> groups of 4 consecutive d
    const size_t obase = ((size_t)b * SS + qrow) * 1024 + hh * 64;
#pragma unroll
    for (int dt = 0; dt < 2; ++dt)
#pragma unroll
        for (int g = 0; g < 4; ++g) {
            int d0 = dt * 32 + 8 * g + 4 * hfl;
            ushort4 pk;
            pk.x = f2bf(oacc[dt][4 * g + 0] * inv);
            pk.y = f2bf(oacc[dt][4 * g + 1] * inv);
            pk.z = f2bf(oacc[dt][4 * g + 2] * inv);
            pk.w = f2bf(oacc[dt][4 * g + 3] * inv);
            *(ushort4*)&Out[obase + d0] = pk;
        }
}

// ---------------- launch ----------------
extern "C" void kernel_launch(void* const* d_in, const int* in_sizes, int n_in,
                              void* d_out, int out_size, void* d_ws, size_t ws_size,
                              hipStream_t stream) {
    const float* x    = (const float*)d_in[0];
    const float* wqkv = (const float*)d_in[1];
    const float* wo   = (const float*)d_in[2];

    unsigned short* ws  = (unsigned short*)d_ws;
    unsigned short* xb  = ws;                    // 8192x1024 bf16
    unsigned short* w1  = ws + 8388608;          // 3072x1024
    unsigned short* w2  = ws + 11534336;         // 1024x1024
    unsigned short* vt  = ws + 12582912;         // 64 heads x 64 d x 2048 s
    unsigned short* ao  = ws + 20971520;         // 8192x1024 attn out
    unsigned short* tqk = (unsigned short*)d_out; // Q|K scratch (bf16), overwritten by final GEMM

    cast3<<<12288, 256, 0, stream>>>(x, wqkv, wo, xb, w1, w2);
    gemm_bt<0><<<dim3(64, 24), 256, 0, stream>>>(xb, w1, (void*)tqk, vt, 1024);
    attn_kernel<<<1024, 256, 0, stream>>>(tqk, vt, ao);
    gemm_bt<1><<<dim3(64, 8), 256, 0, stream>>>(ao, w2, d_out, nullptr, 1024);
}